// Round 1
// baseline (7711.240 us; speedup 1.0000x reference)
//
#include <hip/hip_runtime.h>
#include <cmath>

// SimpleHeteroGNN on MI355X — Round 1: fp32 correctness baseline.
// Structure: input linears -> 5x (scatter-atomic aggregate + fused SAGE update)
// -> fused edge MLP (gather + p1 GEMM + BN + relu + p2 dot + sigmoid).
// GEMM scheme everywhere: one wave handles 8 rows x 128 cols; row activations
// read via wave-uniform scalar loads (s_load, scalar pipe), W streamed from L2,
// acc[8][2] in VGPRs -> ~85% FMA density on the vector pipe.

#define NUSR 100000
#define NMOV 20000
#define NEDG 1000000
#define NEUU 500000
#define DH 128

// ---------------- Y[N,128] = relu(X[N,K] @ W[K,128] + b) ----------------
template <int K>
__global__ __launch_bounds__(256) void lin_relu_k(
    const float* __restrict__ X, const float* __restrict__ W,
    const float* __restrict__ b, float* __restrict__ Y, int N)
{
  const int wave = threadIdx.x >> 6;
  const int lane = threadIdx.x & 63;
  const long row0 = ((long)blockIdx.x * 4 + wave) * 8;
  if (row0 >= N) return;
  const int c0 = lane, c1 = lane + 64;
  float acc[8][2];
#pragma unroll
  for (int r = 0; r < 8; ++r) { acc[r][0] = 0.f; acc[r][1] = 0.f; }
#pragma unroll 4
  for (int k = 0; k < K; ++k) {
    float w0 = W[k * DH + c0];
    float w1 = W[k * DH + c1];
#pragma unroll
    for (int r = 0; r < 8; ++r) {
      float xv = X[(row0 + r) * K + k];  // wave-uniform -> scalar load
      acc[r][0] = fmaf(xv, w0, acc[r][0]);
      acc[r][1] = fmaf(xv, w1, acc[r][1]);
    }
  }
  float b0 = b[c0], b1 = b[c1];
#pragma unroll
  for (int r = 0; r < 8; ++r) {
    Y[(row0 + r) * DH + c0] = fmaxf(acc[r][0] + b0, 0.f);
    Y[(row0 + r) * DH + c1] = fmaxf(acc[r][1] + b1, 0.f);
  }
}

// ---------------- degree count: deg[dst[e]] += 1 ----------------
__global__ __launch_bounds__(256) void deg_k(
    const int* __restrict__ dst, float* __restrict__ deg, int nE)
{
  int e = blockIdx.x * 256 + threadIdx.x;
  if (e < nE) atomicAdd(&deg[dst[e]], 1.0f);
}

// ---------------- scatter: agg[dst[e], :] += xsrc[src[e], :] ----------------
// one wave per edge; lanes cover cols (l, l+64)
__global__ __launch_bounds__(256) void scatter_add_k(
    const float* __restrict__ xsrc, const int* __restrict__ src,
    const int* __restrict__ dst, float* __restrict__ agg, int nE)
{
  long t = (long)blockIdx.x * 256 + threadIdx.x;
  long e = t >> 6;
  int l = (int)(t & 63);
  if (e >= nE) return;
  int s = src[e];  // wave-uniform -> scalar load
  int d = dst[e];
  float v0 = xsrc[(long)s * DH + l];
  float v1 = xsrc[(long)s * DH + 64 + l];
  atomicAdd(&agg[(long)d * DH + l], v0);
  atomicAdd(&agg[(long)d * DH + 64 + l], v1);
}

// ------- out[row,:] = relu((agg[row,:]/max(deg,1)) @ Wl + xdst[row,:] @ Wr + bl)
// in-place safe (out may alias xdst): each wave reads only its own rows.
__global__ __launch_bounds__(256) void sage_update_k(
    const float* __restrict__ agg, const float* __restrict__ deg,
    const float* __restrict__ xdst, const float* __restrict__ Wl,
    const float* __restrict__ bl, const float* __restrict__ Wr,
    float* __restrict__ out, int N)
{
  const int wave = threadIdx.x >> 6;
  const int lane = threadIdx.x & 63;
  const long row0 = ((long)blockIdx.x * 4 + wave) * 8;
  if (row0 >= N) return;
  const int c0 = lane, c1 = lane + 64;
  float inv[8];
#pragma unroll
  for (int r = 0; r < 8; ++r) inv[r] = 1.f / fmaxf(deg[row0 + r], 1.f);
  float acc[8][2];
#pragma unroll
  for (int r = 0; r < 8; ++r) { acc[r][0] = 0.f; acc[r][1] = 0.f; }
#pragma unroll 2
  for (int k = 0; k < DH; ++k) {
    float wl0 = Wl[k * DH + c0], wl1 = Wl[k * DH + c1];
    float wr0 = Wr[k * DH + c0], wr1 = Wr[k * DH + c1];
#pragma unroll
    for (int r = 0; r < 8; ++r) {
      float av = agg[(row0 + r) * DH + k] * inv[r];  // scalar loads
      float xv = xdst[(row0 + r) * DH + k];
      acc[r][0] = fmaf(av, wl0, acc[r][0]);
      acc[r][0] = fmaf(xv, wr0, acc[r][0]);
      acc[r][1] = fmaf(av, wl1, acc[r][1]);
      acc[r][1] = fmaf(xv, wr1, acc[r][1]);
    }
  }
  float b0 = bl[c0], b1 = bl[c1];
#pragma unroll
  for (int r = 0; r < 8; ++r) {
    out[(row0 + r) * DH + c0] = fmaxf(acc[r][0] + b0, 0.f);
    out[(row0 + r) * DH + c1] = fmaxf(acc[r][1] + b1, 0.f);
  }
}

// ---------------- fused edge MLP ----------------
// emb = [ux[src[e]], mx[dst[e]]] (256); h = BNrelu(emb@p1_W + p1_b);
// out = sigmoid(h@p2_W + p2_b)*4 + 1
__global__ __launch_bounds__(256) void edge_mlp_k(
    const float* __restrict__ ux, const float* __restrict__ mx,
    const int* __restrict__ esrc, const int* __restrict__ edst,
    const float* __restrict__ p1W, const float* __restrict__ p1b,
    const float* __restrict__ gamma, const float* __restrict__ beta,
    const float* __restrict__ mean, const float* __restrict__ var,
    const float* __restrict__ p2W, const float* __restrict__ p2b,
    float* __restrict__ out, int nE)
{
  const int wave = threadIdx.x >> 6;
  const int lane = threadIdx.x & 63;
  const long row0 = ((long)blockIdx.x * 4 + wave) * 8;
  if (row0 >= nE) return;
  const int c0 = lane, c1 = lane + 64;
  long ub[8], mb[8];
#pragma unroll
  for (int r = 0; r < 8; ++r) {
    ub[r] = (long)esrc[row0 + r] * DH;  // wave-uniform
    mb[r] = (long)edst[row0 + r] * DH;
  }
  float acc[8][2];
#pragma unroll
  for (int r = 0; r < 8; ++r) { acc[r][0] = 0.f; acc[r][1] = 0.f; }
#pragma unroll 2
  for (int k = 0; k < DH; ++k) {
    float wu0 = p1W[k * DH + c0], wu1 = p1W[k * DH + c1];
    float wm0 = p1W[(k + DH) * DH + c0], wm1 = p1W[(k + DH) * DH + c1];
#pragma unroll
    for (int r = 0; r < 8; ++r) {
      float uv = ux[ub[r] + k];
      float mv = mx[mb[r] + k];
      acc[r][0] = fmaf(uv, wu0, acc[r][0]);
      acc[r][0] = fmaf(mv, wm0, acc[r][0]);
      acc[r][1] = fmaf(uv, wu1, acc[r][1]);
      acc[r][1] = fmaf(mv, wm1, acc[r][1]);
    }
  }
  // epilogue: BN (eval) + relu + p2 dot + sigmoid*4+1
  float sc0 = gamma[c0] * rsqrtf(var[c0] + 1e-5f);
  float sc1 = gamma[c1] * rsqrtf(var[c1] + 1e-5f);
  float sh0 = beta[c0] - mean[c0] * sc0;
  float sh1 = beta[c1] - mean[c1] * sc1;
  float b0 = p1b[c0], b1 = p1b[c1];
  float w20 = p2W[c0], w21 = p2W[c1];
  float bias2 = p2b[0];
#pragma unroll
  for (int r = 0; r < 8; ++r) {
    float h0 = fmaxf((acc[r][0] + b0) * sc0 + sh0, 0.f);
    float h1 = fmaxf((acc[r][1] + b1) * sc1 + sh1, 0.f);
    float part = h0 * w20 + h1 * w21;
    part += __shfl_down(part, 32, 64);
    part += __shfl_down(part, 16, 64);
    part += __shfl_down(part, 8, 64);
    part += __shfl_down(part, 4, 64);
    part += __shfl_down(part, 2, 64);
    part += __shfl_down(part, 1, 64);
    if (lane == 0) out[row0 + r] = 4.f / (1.f + expf(-(part + bias2))) + 1.f;
  }
}

extern "C" void kernel_launch(void* const* d_in, const int* in_sizes, int n_in,
                              void* d_out, int out_size, void* d_ws, size_t ws_size,
                              hipStream_t stream)
{
  const float* user_feat = (const float*)d_in[0];
  const float* movie_feat = (const float*)d_in[1];
  const float* W_user = (const float*)d_in[2];
  const float* b_user = (const float*)d_in[3];
  const float* W_movie = (const float*)d_in[4];
  const float* b_movie = (const float*)d_in[5];
  const float* u2m1_Wl = (const float*)d_in[6];
  const float* u2m1_bl = (const float*)d_in[7];
  const float* u2m1_Wr = (const float*)d_in[8];
  const float* m2u1_Wl = (const float*)d_in[9];
  const float* m2u1_bl = (const float*)d_in[10];
  const float* m2u1_Wr = (const float*)d_in[11];
  const float* u2m2_Wl = (const float*)d_in[12];
  const float* u2m2_bl = (const float*)d_in[13];
  const float* u2m2_Wr = (const float*)d_in[14];
  const float* m2u2_Wl = (const float*)d_in[15];
  const float* m2u2_bl = (const float*)d_in[16];
  const float* m2u2_Wr = (const float*)d_in[17];
  const float* u2u_Wl = (const float*)d_in[18];
  const float* u2u_bl = (const float*)d_in[19];
  const float* u2u_Wr = (const float*)d_in[20];
  const float* p1_W = (const float*)d_in[21];
  const float* p1_b = (const float*)d_in[22];
  const float* bn_gamma = (const float*)d_in[23];
  const float* bn_beta = (const float*)d_in[24];
  const float* bn_mean = (const float*)d_in[25];
  const float* bn_var = (const float*)d_in[26];
  const float* p2_W = (const float*)d_in[27];
  const float* p2_b = (const float*)d_in[28];
  const int* rated_src = (const int*)d_in[29];
  const int* rated_dst = (const int*)d_in[30];
  const int* uu_src = (const int*)d_in[31];
  const int* uu_dst = (const int*)d_in[32];

  // workspace layout (fp32): ux[NU*128] mx[NM*128] agg[NU*128] deg_m[NM] deg_u[NU] deg_uu[NU]
  float* ux = (float*)d_ws;
  float* mx = ux + (size_t)NUSR * DH;
  float* agg = mx + (size_t)NMOV * DH;
  float* deg_m = agg + (size_t)NUSR * DH;
  float* deg_u = deg_m + NMOV;
  float* deg_uu = deg_u + NUSR;

  // degree counts (once; reused across layers). contiguous -> one memset.
  hipMemsetAsync(deg_m, 0, (size_t)(NMOV + 2 * NUSR) * sizeof(float), stream);
  deg_k<<<(NEDG + 255) / 256, 256, 0, stream>>>(rated_dst, deg_m, NEDG);
  deg_k<<<(NEDG + 255) / 256, 256, 0, stream>>>(rated_src, deg_u, NEDG);
  deg_k<<<(NEUU + 255) / 256, 256, 0, stream>>>(uu_dst, deg_uu, NEUU);

  // input linears
  lin_relu_k<64><<<NUSR / 32, 256, 0, stream>>>(user_feat, W_user, b_user, ux, NUSR);
  lin_relu_k<128><<<NMOV / 32, 256, 0, stream>>>(movie_feat, W_movie, b_movie, mx, NMOV);

  // u2m1: msg = ux[rated_src] aggregated at movies by rated_dst
  hipMemsetAsync(agg, 0, (size_t)NMOV * DH * sizeof(float), stream);
  scatter_add_k<<<NEDG / 4, 256, 0, stream>>>(ux, rated_src, rated_dst, agg, NEDG);
  sage_update_k<<<NMOV / 32, 256, 0, stream>>>(agg, deg_m, mx, u2m1_Wl, u2m1_bl, u2m1_Wr, mx, NMOV);

  // m2u1: msg = mx[rated_dst] aggregated at users by rated_src
  hipMemsetAsync(agg, 0, (size_t)NUSR * DH * sizeof(float), stream);
  scatter_add_k<<<NEDG / 4, 256, 0, stream>>>(mx, rated_dst, rated_src, agg, NEDG);
  sage_update_k<<<NUSR / 32, 256, 0, stream>>>(agg, deg_u, ux, m2u1_Wl, m2u1_bl, m2u1_Wr, ux, NUSR);

  // u2m2
  hipMemsetAsync(agg, 0, (size_t)NMOV * DH * sizeof(float), stream);
  scatter_add_k<<<NEDG / 4, 256, 0, stream>>>(ux, rated_src, rated_dst, agg, NEDG);
  sage_update_k<<<NMOV / 32, 256, 0, stream>>>(agg, deg_m, mx, u2m2_Wl, u2m2_bl, u2m2_Wr, mx, NMOV);

  // m2u2
  hipMemsetAsync(agg, 0, (size_t)NUSR * DH * sizeof(float), stream);
  scatter_add_k<<<NEDG / 4, 256, 0, stream>>>(mx, rated_dst, rated_src, agg, NEDG);
  sage_update_k<<<NUSR / 32, 256, 0, stream>>>(agg, deg_u, ux, m2u2_Wl, m2u2_bl, m2u2_Wr, ux, NUSR);

  // u2u: msg = ux[uu_src] aggregated at users by uu_dst
  hipMemsetAsync(agg, 0, (size_t)NUSR * DH * sizeof(float), stream);
  scatter_add_k<<<NEUU / 4, 256, 0, stream>>>(ux, uu_src, uu_dst, agg, NEUU);
  sage_update_k<<<NUSR / 32, 256, 0, stream>>>(agg, deg_uu, ux, u2u_Wl, u2u_bl, u2u_Wr, ux, NUSR);

  // fused edge MLP -> output
  edge_mlp_k<<<NEDG / 32, 256, 0, stream>>>(
      ux, mx, rated_src, rated_dst, p1_W, p1_b,
      bn_gamma, bn_beta, bn_mean, bn_var, p2_W, p2_b,
      (float*)d_out, NEDG);
}

// Round 2
// 1474.824 us; speedup vs baseline: 5.2286x; 5.2286x over previous
//
#include <hip/hip_runtime.h>
#include <cmath>

// SimpleHeteroGNN on MI355X — Round 2: bf16 MFMA GEMMs + CSR gather-mean aggregation.
//
// Changes vs R1 (theory: edge_mlp latency-bound fp32 -> MFMA; scatter atomics -> CSR gather):
//  - node activations ux/mx stored bf16 (ushort), fp32 accumulate everywhere
//  - 5x SAGE update and edge MLP are K=256 MFMA GEMMs (16x16x32_bf16),
//    weights pre-transposed to [n][k] bf16, staged in LDS (row stride 264 -> 2-way banks)
//  - aggregation: CSR built on device (hist + single-block scan + cursor fill),
//    then one wave per dst row gather-sum (bf16x2 loads, fp32 acc, mean, bf16 store)

#define NUSR 100000
#define NMOV 20000
#define NEDG 1000000
#define NEUU 500000
#define DH 128

typedef unsigned short ushort_t;
typedef __attribute__((ext_vector_type(8))) short short8;
typedef __attribute__((ext_vector_type(4))) float f32x4;

__device__ __forceinline__ float bf2f(ushort_t u) {
  return __uint_as_float(((unsigned)u) << 16);
}
__device__ __forceinline__ ushort_t f2bf(float f) {
  unsigned u = __float_as_uint(f);
  u += 0x7FFFu + ((u >> 16) & 1u);
  return (ushort_t)(u >> 16);
}

// ---------- weight prep: Wt[n*256+k] = bf16( k<128 ? Wl[k][n] : Wr[k-128][n] ) ----------
__global__ __launch_bounds__(256) void prep_w_k(
    const float* __restrict__ Wl, const float* __restrict__ Wr,
    ushort_t* __restrict__ Wt)
{
  int idx = blockIdx.x * 256 + threadIdx.x;  // 0..32767
  int n = idx >> 8, k = idx & 255;
  float v = (k < DH) ? Wl[k * DH + n] : Wr[(k - DH) * DH + n];
  Wt[n * 256 + k] = f2bf(v);
}

// ---------- input linear: Y = relu(X @ W + b), bf16 out ----------
template <int K>
__global__ __launch_bounds__(256) void lin_relu_bf_k(
    const float* __restrict__ X, const float* __restrict__ W,
    const float* __restrict__ b, ushort_t* __restrict__ Y, int N)
{
  const int wave = threadIdx.x >> 6;
  const int lane = threadIdx.x & 63;
  const long row0 = ((long)blockIdx.x * 4 + wave) * 8;
  if (row0 >= N) return;
  const int c0 = lane, c1 = lane + 64;
  float acc[8][2];
#pragma unroll
  for (int r = 0; r < 8; ++r) { acc[r][0] = 0.f; acc[r][1] = 0.f; }
#pragma unroll 4
  for (int k = 0; k < K; ++k) {
    float w0 = W[k * DH + c0];
    float w1 = W[k * DH + c1];
#pragma unroll
    for (int r = 0; r < 8; ++r) {
      float xv = X[(row0 + r) * K + k];
      acc[r][0] = fmaf(xv, w0, acc[r][0]);
      acc[r][1] = fmaf(xv, w1, acc[r][1]);
    }
  }
  float b0 = b[c0], b1 = b[c1];
#pragma unroll
  for (int r = 0; r < 8; ++r) {
    Y[(row0 + r) * DH + c0] = f2bf(fmaxf(acc[r][0] + b0, 0.f));
    Y[(row0 + r) * DH + c1] = f2bf(fmaxf(acc[r][1] + b1, 0.f));
  }
}

// ---------- CSR build ----------
__global__ __launch_bounds__(256) void count_k(
    const int* __restrict__ idx, int* __restrict__ cnt, int nE)
{
  int e = blockIdx.x * 256 + threadIdx.x;
  if (e < nE) atomicAdd(&cnt[idx[e]], 1);
}

// single-block exclusive scan (n up to ~100k)
__global__ __launch_bounds__(1024) void scan_k(
    const int* __restrict__ cnt, int* __restrict__ rowptr, int n)
{
  __shared__ int part[1024];
  const int t = threadIdx.x;
  const int chunk = (n + 1023) >> 10;
  int b = t * chunk;
  int e = b + chunk; if (e > n) e = n; if (b > n) b = n;
  int s = 0;
  for (int i = b; i < e; ++i) s += cnt[i];
  part[t] = s;
  __syncthreads();
  for (int off = 1; off < 1024; off <<= 1) {
    int v = (t >= off) ? part[t - off] : 0;
    __syncthreads();
    part[t] += v;
    __syncthreads();
  }
  int excl = part[t] - s;
  for (int i = b; i < e; ++i) { rowptr[i] = excl; excl += cnt[i]; }
  if (t == 0) rowptr[n] = part[1023];
}

__global__ __launch_bounds__(256) void fill_k(
    const int* __restrict__ dstI, const int* __restrict__ srcI,
    const int* __restrict__ rowptr, int* __restrict__ cur,
    int* __restrict__ col, int nE)
{
  int e = blockIdx.x * 256 + threadIdx.x;
  if (e < nE) {
    int d = dstI[e];
    int pos = rowptr[d] + atomicAdd(&cur[d], 1);
    col[pos] = srcI[e];
  }
}

// ---------- gather-mean: out[row,:] = mean over incident edges of x[col[i],:] ----------
// one wave per row; lane covers cols (2*lane, 2*lane+1)
__global__ __launch_bounds__(256) void agg_mean_k(
    const ushort_t* __restrict__ x, const int* __restrict__ rowptr,
    const int* __restrict__ col, ushort_t* __restrict__ out, int N)
{
  const int wave = threadIdx.x >> 6;
  const int lane = threadIdx.x & 63;
  const int row = blockIdx.x * 4 + wave;
  if (row >= N) return;
  const int b = rowptr[row], e = rowptr[row + 1];
  float a0 = 0.f, a1 = 0.f;
  int i = b;
  for (; i + 1 < e; i += 2) {
    int s0 = col[i], s1 = col[i + 1];
    unsigned v0 = *(const unsigned*)(x + (size_t)s0 * DH + lane * 2);
    unsigned v1 = *(const unsigned*)(x + (size_t)s1 * DH + lane * 2);
    a0 += __uint_as_float(v0 << 16) + __uint_as_float(v1 << 16);
    a1 += __uint_as_float(v0 & 0xFFFF0000u) + __uint_as_float(v1 & 0xFFFF0000u);
  }
  if (i < e) {
    unsigned v0 = *(const unsigned*)(x + (size_t)col[i] * DH + lane * 2);
    a0 += __uint_as_float(v0 << 16);
    a1 += __uint_as_float(v0 & 0xFFFF0000u);
  }
  int deg = e - b;
  float inv = 1.f / (float)(deg > 1 ? deg : 1);
  unsigned lo = f2bf(a0 * inv), hi = f2bf(a1 * inv);
  *(unsigned*)(out + (size_t)row * DH + lane * 2) = lo | (hi << 16);
}

// ---------- SAGE update GEMM: out = relu([A0|A1] @ WtT + bl), bf16, in-place-safe ----------
// block = 4 waves; wave = 32 rows x 128 cols; K=256 (first 128 from A0, rest A1)
__global__ __launch_bounds__(256) void sage_mfma_k(
    const ushort_t* __restrict__ A0, const ushort_t* __restrict__ A1,
    const ushort_t* __restrict__ Wt, const float* __restrict__ bl,
    ushort_t* __restrict__ out, int N)
{
  __shared__ ushort_t ldsw[128 * 264];
  // stage Wt (128 n-rows x 256 k) into LDS, row stride 264 (16B pad)
  for (int c = threadIdx.x; c < 128 * 32; c += 256) {
    int r = c >> 5, cc = c & 31;
    *(int4*)&ldsw[r * 264 + cc * 8] = *(const int4*)&Wt[r * 256 + cc * 8];
  }
  __syncthreads();

  const int wave = threadIdx.x >> 6;
  const int lane = threadIdx.x & 63;
  const int row0 = (blockIdx.x * 4 + wave) * 32;
  if (row0 >= N) return;
  const int lm = lane & 15;
  const int koff = (lane >> 4) * 8;

  size_t abase[2];
#pragma unroll
  for (int a = 0; a < 2; ++a) abase[a] = (size_t)(row0 + a * 16 + lm) * DH;

  f32x4 acc[2][8];
#pragma unroll
  for (int a = 0; a < 2; ++a)
#pragma unroll
    for (int nt = 0; nt < 8; ++nt) acc[a][nt] = (f32x4){0.f, 0.f, 0.f, 0.f};

#pragma unroll
  for (int ks = 0; ks < 8; ++ks) {
    short8 af[2];
#pragma unroll
    for (int a = 0; a < 2; ++a) {
      const ushort_t* p = (ks < 4) ? (A0 + abase[a] + ks * 32 + koff)
                                   : (A1 + abase[a] + (ks - 4) * 32 + koff);
      af[a] = *(const short8*)p;
    }
#pragma unroll
    for (int nt = 0; nt < 8; ++nt) {
      short8 bf = *(const short8*)&ldsw[(nt * 16 + lm) * 264 + ks * 32 + koff];
      acc[0][nt] = __builtin_amdgcn_mfma_f32_16x16x32_bf16(af[0], bf, acc[0][nt], 0, 0, 0);
      acc[1][nt] = __builtin_amdgcn_mfma_f32_16x16x32_bf16(af[1], bf, acc[1][nt], 0, 0, 0);
    }
  }

  // epilogue: relu(acc + bl), store bf16. C/D: col=lane&15, row=(lane>>4)*4+reg
  const int quad = lane >> 4;
#pragma unroll
  for (int nt = 0; nt < 8; ++nt) {
    int f = nt * 16 + lm;
    float bv = bl[f];
#pragma unroll
    for (int a = 0; a < 2; ++a) {
#pragma unroll
      for (int reg = 0; reg < 4; ++reg) {
        int r = row0 + a * 16 + quad * 4 + reg;
        out[(size_t)r * DH + f] = f2bf(fmaxf(acc[a][nt][reg] + bv, 0.f));
      }
    }
  }
}

// ---------- edge MLP: gathered [ux[src]|mx[dst]] @ p1Wt -> BN -> relu -> p2 -> sigmoid ----------
__global__ __launch_bounds__(256) void edge_mlp_mfma_k(
    const ushort_t* __restrict__ ux, const ushort_t* __restrict__ mx,
    const int* __restrict__ esrc, const int* __restrict__ edst,
    const ushort_t* __restrict__ Wt, const float* __restrict__ p1b,
    const float* __restrict__ gamma, const float* __restrict__ beta,
    const float* __restrict__ mean, const float* __restrict__ var,
    const float* __restrict__ p2W, const float* __restrict__ p2b,
    float* __restrict__ out, int nE)
{
  __shared__ ushort_t ldsw[128 * 264];
  for (int c = threadIdx.x; c < 128 * 32; c += 256) {
    int r = c >> 5, cc = c & 31;
    *(int4*)&ldsw[r * 264 + cc * 8] = *(const int4*)&Wt[r * 256 + cc * 8];
  }
  __syncthreads();

  const int wave = threadIdx.x >> 6;
  const int lane = threadIdx.x & 63;
  const int row0 = (blockIdx.x * 4 + wave) * 32;
  if (row0 >= nE) return;
  const int lm = lane & 15;
  const int koff = (lane >> 4) * 8;

  size_t ubase[2], mbase[2];
#pragma unroll
  for (int a = 0; a < 2; ++a) {
    int e = row0 + a * 16 + lm;
    ubase[a] = (size_t)esrc[e] * DH;
    mbase[a] = (size_t)edst[e] * DH;
  }

  f32x4 acc[2][8];
#pragma unroll
  for (int a = 0; a < 2; ++a)
#pragma unroll
    for (int nt = 0; nt < 8; ++nt) acc[a][nt] = (f32x4){0.f, 0.f, 0.f, 0.f};

#pragma unroll
  for (int ks = 0; ks < 8; ++ks) {
    short8 af[2];
#pragma unroll
    for (int a = 0; a < 2; ++a) {
      const ushort_t* p = (ks < 4) ? (ux + ubase[a] + ks * 32 + koff)
                                   : (mx + mbase[a] + (ks - 4) * 32 + koff);
      af[a] = *(const short8*)p;
    }
#pragma unroll
    for (int nt = 0; nt < 8; ++nt) {
      short8 bf = *(const short8*)&ldsw[(nt * 16 + lm) * 264 + ks * 32 + koff];
      acc[0][nt] = __builtin_amdgcn_mfma_f32_16x16x32_bf16(af[0], bf, acc[0][nt], 0, 0, 0);
      acc[1][nt] = __builtin_amdgcn_mfma_f32_16x16x32_bf16(af[1], bf, acc[1][nt], 0, 0, 0);
    }
  }

  // per-lane epilogue params for features f = nt*16 + lm
  float S[8], T[8], w2[8];
#pragma unroll
  for (int nt = 0; nt < 8; ++nt) {
    int f = nt * 16 + lm;
    float sc = gamma[f] * rsqrtf(var[f] + 1e-5f);
    S[nt] = sc;
    T[nt] = (p1b[f] - mean[f]) * sc + beta[f];
    w2[nt] = p2W[f];
  }
  const float bias2 = p2b[0];
  const int quad = lane >> 4;

#pragma unroll
  for (int a = 0; a < 2; ++a) {
#pragma unroll
    for (int reg = 0; reg < 4; ++reg) {
      float p = 0.f;
#pragma unroll
      for (int nt = 0; nt < 8; ++nt) {
        float h = fmaxf(acc[a][nt][reg] * S[nt] + T[nt], 0.f);
        p += h * w2[nt];
      }
      // reduce across the 16 lanes of this quad (contiguous lanes)
      p += __shfl_xor(p, 1, 16);
      p += __shfl_xor(p, 2, 16);
      p += __shfl_xor(p, 4, 16);
      p += __shfl_xor(p, 8, 16);
      if (lm == 0) {
        int e = row0 + a * 16 + quad * 4 + reg;
        out[e] = 4.f / (1.f + expf(-(p + bias2))) + 1.f;
      }
    }
  }
}

extern "C" void kernel_launch(void* const* d_in, const int* in_sizes, int n_in,
                              void* d_out, int out_size, void* d_ws, size_t ws_size,
                              hipStream_t stream)
{
  const float* user_feat = (const float*)d_in[0];
  const float* movie_feat = (const float*)d_in[1];
  const float* W_user = (const float*)d_in[2];
  const float* b_user = (const float*)d_in[3];
  const float* W_movie = (const float*)d_in[4];
  const float* b_movie = (const float*)d_in[5];
  const float* u2m1_Wl = (const float*)d_in[6];
  const float* u2m1_bl = (const float*)d_in[7];
  const float* u2m1_Wr = (const float*)d_in[8];
  const float* m2u1_Wl = (const float*)d_in[9];
  const float* m2u1_bl = (const float*)d_in[10];
  const float* m2u1_Wr = (const float*)d_in[11];
  const float* u2m2_Wl = (const float*)d_in[12];
  const float* u2m2_bl = (const float*)d_in[13];
  const float* u2m2_Wr = (const float*)d_in[14];
  const float* m2u2_Wl = (const float*)d_in[15];
  const float* m2u2_bl = (const float*)d_in[16];
  const float* m2u2_Wr = (const float*)d_in[17];
  const float* u2u_Wl = (const float*)d_in[18];
  const float* u2u_bl = (const float*)d_in[19];
  const float* u2u_Wr = (const float*)d_in[20];
  const float* p1_W = (const float*)d_in[21];
  const float* p1_b = (const float*)d_in[22];
  const float* bn_gamma = (const float*)d_in[23];
  const float* bn_beta = (const float*)d_in[24];
  const float* bn_mean = (const float*)d_in[25];
  const float* bn_var = (const float*)d_in[26];
  const float* p2_W = (const float*)d_in[27];
  const float* p2_b = (const float*)d_in[28];
  const int* rated_src = (const int*)d_in[29];
  const int* rated_dst = (const int*)d_in[30];
  const int* uu_src = (const int*)d_in[31];
  const int* uu_dst = (const int*)d_in[32];

  // ---- workspace layout ----
  ushort_t* ux = (ushort_t*)d_ws;                       // NU*128
  ushort_t* mx = ux + (size_t)NUSR * DH;                // NM*128
  ushort_t* agg = mx + (size_t)NMOV * DH;               // NU*128
  ushort_t* Wt = agg + (size_t)NUSR * DH;               // 6 * 128*256
  int* rp_m = (int*)(Wt + 6 * 32768);                   // NM+1
  int* rp_u = rp_m + (NMOV + 1);                        // NU+1
  int* rp_uu = rp_u + (NUSR + 1);                       // NU+1
  int* col_m = rp_uu + (NUSR + 1);                      // E
  int* col_u = col_m + NEDG;                            // E
  int* col_uu = col_u + NEDG;                           // EUU
  int* cnt = col_uu + NEUU;                             // NU (counts, then cursor)

  ushort_t* Wt_u2m1 = Wt + 0 * 32768;
  ushort_t* Wt_m2u1 = Wt + 1 * 32768;
  ushort_t* Wt_u2m2 = Wt + 2 * 32768;
  ushort_t* Wt_m2u2 = Wt + 3 * 32768;
  ushort_t* Wt_u2u  = Wt + 4 * 32768;
  ushort_t* Wt_p1   = Wt + 5 * 32768;

  // ---- weight prep (bf16, transposed k-contiguous) ----
  prep_w_k<<<128, 256, 0, stream>>>(u2m1_Wl, u2m1_Wr, Wt_u2m1);
  prep_w_k<<<128, 256, 0, stream>>>(m2u1_Wl, m2u1_Wr, Wt_m2u1);
  prep_w_k<<<128, 256, 0, stream>>>(u2m2_Wl, u2m2_Wr, Wt_u2m2);
  prep_w_k<<<128, 256, 0, stream>>>(m2u2_Wl, m2u2_Wr, Wt_m2u2);
  prep_w_k<<<128, 256, 0, stream>>>(u2u_Wl, u2u_Wr, Wt_u2u);
  prep_w_k<<<128, 256, 0, stream>>>(p1_W, p1_W + DH * DH, Wt_p1);

  // ---- input linears ----
  lin_relu_bf_k<64><<<NUSR / 32, 256, 0, stream>>>(user_feat, W_user, b_user, ux, NUSR);
  lin_relu_bf_k<128><<<NMOV / 32, 256, 0, stream>>>(movie_feat, W_movie, b_movie, mx, NMOV);

  // ---- CSR builds (3 graphs) ----
  const int gcE = (NEDG + 255) / 256, gcU = (NEUU + 255) / 256;
  // movie-rows CSR: dst=rated_dst, store src=rated_src
  hipMemsetAsync(cnt, 0, NMOV * sizeof(int), stream);
  count_k<<<gcE, 256, 0, stream>>>(rated_dst, cnt, NEDG);
  scan_k<<<1, 1024, 0, stream>>>(cnt, rp_m, NMOV);
  hipMemsetAsync(cnt, 0, NMOV * sizeof(int), stream);
  fill_k<<<gcE, 256, 0, stream>>>(rated_dst, rated_src, rp_m, cnt, col_m, NEDG);
  // user-rows CSR: dst=rated_src, store=rated_dst
  hipMemsetAsync(cnt, 0, NUSR * sizeof(int), stream);
  count_k<<<gcE, 256, 0, stream>>>(rated_src, cnt, NEDG);
  scan_k<<<1, 1024, 0, stream>>>(cnt, rp_u, NUSR);
  hipMemsetAsync(cnt, 0, NUSR * sizeof(int), stream);
  fill_k<<<gcE, 256, 0, stream>>>(rated_src, rated_dst, rp_u, cnt, col_u, NEDG);
  // uu CSR: dst=uu_dst, store=uu_src
  hipMemsetAsync(cnt, 0, NUSR * sizeof(int), stream);
  count_k<<<gcU, 256, 0, stream>>>(uu_dst, cnt, NEUU);
  scan_k<<<1, 1024, 0, stream>>>(cnt, rp_uu, NUSR);
  hipMemsetAsync(cnt, 0, NUSR * sizeof(int), stream);
  fill_k<<<gcU, 256, 0, stream>>>(uu_dst, uu_src, rp_uu, cnt, col_uu, NEUU);

  // ---- 5 SAGE layers ----
  const int gbM = (NMOV + 3) / 4, gbU = (NUSR + 3) / 4;
  const int gmM = (NMOV + 127) / 128, gmU = (NUSR + 127) / 128;
  // u2m1
  agg_mean_k<<<gbM, 256, 0, stream>>>(ux, rp_m, col_m, agg, NMOV);
  sage_mfma_k<<<gmM, 256, 0, stream>>>(agg, mx, Wt_u2m1, u2m1_bl, mx, NMOV);
  // m2u1
  agg_mean_k<<<gbU, 256, 0, stream>>>(mx, rp_u, col_u, agg, NUSR);
  sage_mfma_k<<<gmU, 256, 0, stream>>>(agg, ux, Wt_m2u1, m2u1_bl, ux, NUSR);
  // u2m2
  agg_mean_k<<<gbM, 256, 0, stream>>>(ux, rp_m, col_m, agg, NMOV);
  sage_mfma_k<<<gmM, 256, 0, stream>>>(agg, mx, Wt_u2m2, u2m2_bl, mx, NMOV);
  // m2u2
  agg_mean_k<<<gbU, 256, 0, stream>>>(mx, rp_u, col_u, agg, NUSR);
  sage_mfma_k<<<gmU, 256, 0, stream>>>(agg, ux, Wt_m2u2, m2u2_bl, ux, NUSR);
  // u2u
  agg_mean_k<<<gbU, 256, 0, stream>>>(ux, rp_uu, col_uu, agg, NUSR);
  sage_mfma_k<<<gmU, 256, 0, stream>>>(agg, ux, Wt_u2u, u2u_bl, ux, NUSR);

  // ---- edge MLP ----
  edge_mlp_mfma_k<<<(NEDG + 127) / 128, 256, 0, stream>>>(
      ux, mx, rated_src, rated_dst, Wt_p1, p1_b,
      bn_gamma, bn_beta, bn_mean, bn_var, p2_W, p2_b,
      (float*)d_out, NEDG);
}

// Round 3
// 1263.258 us; speedup vs baseline: 6.1042x; 1.1675x over previous
//
#include <hip/hip_runtime.h>
#include <cmath>

// SimpleHeteroGNN on MI355X — Round 3.
//  - edge MLP factored: emb@p1W = ux[src]@Wu + mx[dst]@Wm  ->  two node-level
//    MFMA GEMMs (pu,pm bf16) + CSR-driven per-edge kernel (gather pm row, fused
//    BN/relu/p2-dot/sigmoid). pu loaded once per user row; out[eid] scatter.
//  - agg_mean: 4 rows/wave (one per 16-lane quarter), 2-edge unroll -> 8
//    outstanding 256B gathers per wave (was 2, latency-bound).
//  - sage GEMM: LDS staging dropped (Wt is 64KB, L2-resident); no barrier,
//    occupancy no longer LDS-capped.

#define NUSR 100000
#define NMOV 20000
#define NEDG 1000000
#define NEUU 500000
#define DH 128

typedef unsigned short ushort_t;
typedef __attribute__((ext_vector_type(8))) short short8;
typedef __attribute__((ext_vector_type(4))) float f32x4;

__device__ __forceinline__ ushort_t f2bf(float f) {
  unsigned u = __float_as_uint(f);
  u += 0x7FFFu + ((u >> 16) & 1u);
  return (ushort_t)(u >> 16);
}
__device__ __forceinline__ void bf8_to_f32(int4 v, float* f) {
  unsigned a = (unsigned)v.x, b = (unsigned)v.y, c = (unsigned)v.z, d = (unsigned)v.w;
  f[0] = __uint_as_float(a << 16); f[1] = __uint_as_float(a & 0xFFFF0000u);
  f[2] = __uint_as_float(b << 16); f[3] = __uint_as_float(b & 0xFFFF0000u);
  f[4] = __uint_as_float(c << 16); f[5] = __uint_as_float(c & 0xFFFF0000u);
  f[6] = __uint_as_float(d << 16); f[7] = __uint_as_float(d & 0xFFFF0000u);
}

// ---------- weight prep: Wt[n*256+k] = bf16( k<128 ? Wl[k][n] : Wr[k-128][n] ) ----------
__global__ __launch_bounds__(256) void prep_w_k(
    const float* __restrict__ Wl, const float* __restrict__ Wr,
    ushort_t* __restrict__ Wt)
{
  int idx = blockIdx.x * 256 + threadIdx.x;  // 0..32767
  int n = idx >> 8, k = idx & 255;
  float v = (k < DH) ? Wl[k * DH + n] : Wr[(k - DH) * DH + n];
  Wt[n * 256 + k] = f2bf(v);
}

// ---------- input linear: Y = relu(X @ W + b), bf16 out ----------
template <int K>
__global__ __launch_bounds__(256) void lin_relu_bf_k(
    const float* __restrict__ X, const float* __restrict__ W,
    const float* __restrict__ b, ushort_t* __restrict__ Y, int N)
{
  const int wave = threadIdx.x >> 6;
  const int lane = threadIdx.x & 63;
  const long row0 = ((long)blockIdx.x * 4 + wave) * 8;
  if (row0 >= N) return;
  const int c0 = lane, c1 = lane + 64;
  float acc[8][2];
#pragma unroll
  for (int r = 0; r < 8; ++r) { acc[r][0] = 0.f; acc[r][1] = 0.f; }
#pragma unroll 4
  for (int k = 0; k < K; ++k) {
    float w0 = W[k * DH + c0];
    float w1 = W[k * DH + c1];
#pragma unroll
    for (int r = 0; r < 8; ++r) {
      float xv = X[(row0 + r) * K + k];  // wave-uniform -> scalar load
      acc[r][0] = fmaf(xv, w0, acc[r][0]);
      acc[r][1] = fmaf(xv, w1, acc[r][1]);
    }
  }
  float b0 = b[c0], b1 = b[c1];
#pragma unroll
  for (int r = 0; r < 8; ++r) {
    Y[(row0 + r) * DH + c0] = f2bf(fmaxf(acc[r][0] + b0, 0.f));
    Y[(row0 + r) * DH + c1] = f2bf(fmaxf(acc[r][1] + b1, 0.f));
  }
}

// ---------- CSR build ----------
__global__ __launch_bounds__(256) void count2_k(
    const int* __restrict__ srcI, const int* __restrict__ dstI,
    int* __restrict__ cnt_u, int* __restrict__ cnt_m, int nE)
{
  int e = blockIdx.x * 256 + threadIdx.x;
  if (e < nE) {
    atomicAdd(&cnt_u[srcI[e]], 1);
    atomicAdd(&cnt_m[dstI[e]], 1);
  }
}
__global__ __launch_bounds__(256) void count_k(
    const int* __restrict__ idx, int* __restrict__ cnt, int nE)
{
  int e = blockIdx.x * 256 + threadIdx.x;
  if (e < nE) atomicAdd(&cnt[idx[e]], 1);
}

// single-block exclusive scan (n up to ~100k)
__global__ __launch_bounds__(1024) void scan_k(
    const int* __restrict__ cnt, int* __restrict__ rowptr, int n)
{
  __shared__ int part[1024];
  const int t = threadIdx.x;
  const int chunk = (n + 1023) >> 10;
  int b = t * chunk;
  int e = b + chunk; if (e > n) e = n; if (b > n) b = n;
  int s = 0;
#pragma unroll 4
  for (int i = b; i < e; ++i) s += cnt[i];
  part[t] = s;
  __syncthreads();
  for (int off = 1; off < 1024; off <<= 1) {
    int v = (t >= off) ? part[t - off] : 0;
    __syncthreads();
    part[t] += v;
    __syncthreads();
  }
  int excl = part[t] - s;
  for (int i = b; i < e; ++i) { rowptr[i] = excl; excl += cnt[i]; }
  if (t == 0) rowptr[n] = part[1023];
}

__global__ __launch_bounds__(256) void fill_k(
    const int* __restrict__ dstI, const int* __restrict__ srcI,
    const int* __restrict__ rowptr, int* __restrict__ cur,
    int* __restrict__ col, int* __restrict__ eid, int nE)
{
  int e = blockIdx.x * 256 + threadIdx.x;
  if (e < nE) {
    int d = dstI[e];
    int pos = rowptr[d] + atomicAdd(&cur[d], 1);
    col[pos] = srcI[e];
    if (eid) eid[pos] = e;
  }
}

// ---------- gather-mean: out[row,:] = mean over incident edges of x[col[i],:] ----------
// 4 rows per wave (one per 16-lane quarter); lane covers 8 feats (16B); unroll 2.
__global__ __launch_bounds__(256) void agg_mean4_k(
    const ushort_t* __restrict__ x, const int* __restrict__ rowptr,
    const int* __restrict__ col, ushort_t* __restrict__ out, int N)
{
  const int wave = threadIdx.x >> 6;
  const int lane = threadIdx.x & 63;
  const int lm = lane & 15, q = lane >> 4;
  const int row = blockIdx.x * 16 + wave * 4 + q;
  if (row >= N) return;
  const int b = rowptr[row], e = rowptr[row + 1];
  float a[8];
#pragma unroll
  for (int j = 0; j < 8; ++j) a[j] = 0.f;
  int i = b;
  for (; i + 1 < e; i += 2) {
    int s0 = col[i], s1 = col[i + 1];
    int4 v0 = *(const int4*)(x + (size_t)s0 * DH + lm * 8);
    int4 v1 = *(const int4*)(x + (size_t)s1 * DH + lm * 8);
    float f0[8], f1[8];
    bf8_to_f32(v0, f0); bf8_to_f32(v1, f1);
#pragma unroll
    for (int j = 0; j < 8; ++j) a[j] += f0[j] + f1[j];
  }
  if (i < e) {
    int4 v0 = *(const int4*)(x + (size_t)col[i] * DH + lm * 8);
    float f0[8];
    bf8_to_f32(v0, f0);
#pragma unroll
    for (int j = 0; j < 8; ++j) a[j] += f0[j];
  }
  int deg = e - b;
  float inv = 1.f / (float)(deg > 1 ? deg : 1);
  unsigned p0 = f2bf(a[0] * inv) | ((unsigned)f2bf(a[1] * inv) << 16);
  unsigned p1 = f2bf(a[2] * inv) | ((unsigned)f2bf(a[3] * inv) << 16);
  unsigned p2 = f2bf(a[4] * inv) | ((unsigned)f2bf(a[5] * inv) << 16);
  unsigned p3 = f2bf(a[6] * inv) | ((unsigned)f2bf(a[7] * inv) << 16);
  *(int4*)(out + (size_t)row * DH + lm * 8) = make_int4(p0, p1, p2, p3);
}

// ---------- SAGE update GEMM (no LDS): out = relu([A0|A1] @ WtT + bl) ----------
// wave = 32 rows x 128 cols; K=256; B fragments read straight from L2-resident Wt.
__global__ __launch_bounds__(256) void sage_mfma_k(
    const ushort_t* __restrict__ A0, const ushort_t* __restrict__ A1,
    const ushort_t* __restrict__ Wt, const float* __restrict__ bl,
    ushort_t* __restrict__ out, int N)
{
  const int wave = threadIdx.x >> 6;
  const int lane = threadIdx.x & 63;
  const int row0 = (blockIdx.x * 4 + wave) * 32;
  if (row0 >= N) return;
  const int lm = lane & 15;
  const int koff = (lane >> 4) * 8;

  size_t abase[2];
#pragma unroll
  for (int a = 0; a < 2; ++a) abase[a] = (size_t)(row0 + a * 16 + lm) * DH;

  f32x4 acc[2][8];
#pragma unroll
  for (int a = 0; a < 2; ++a)
#pragma unroll
    for (int nt = 0; nt < 8; ++nt) acc[a][nt] = (f32x4){0.f, 0.f, 0.f, 0.f};

#pragma unroll
  for (int ks = 0; ks < 8; ++ks) {
    short8 af[2];
#pragma unroll
    for (int a = 0; a < 2; ++a) {
      const ushort_t* p = (ks < 4) ? (A0 + abase[a] + ks * 32 + koff)
                                   : (A1 + abase[a] + (ks - 4) * 32 + koff);
      af[a] = *(const short8*)p;
    }
#pragma unroll
    for (int nt = 0; nt < 8; ++nt) {
      short8 bf = *(const short8*)&Wt[(nt * 16 + lm) * 256 + ks * 32 + koff];
      acc[0][nt] = __builtin_amdgcn_mfma_f32_16x16x32_bf16(af[0], bf, acc[0][nt], 0, 0, 0);
      acc[1][nt] = __builtin_amdgcn_mfma_f32_16x16x32_bf16(af[1], bf, acc[1][nt], 0, 0, 0);
    }
  }

  const int quad = lane >> 4;
#pragma unroll
  for (int nt = 0; nt < 8; ++nt) {
    int f = nt * 16 + lm;
    float bv = bl[f];
#pragma unroll
    for (int a = 0; a < 2; ++a) {
#pragma unroll
      for (int reg = 0; reg < 4; ++reg) {
        int r = row0 + a * 16 + quad * 4 + reg;
        out[(size_t)r * DH + f] = f2bf(fmaxf(acc[a][nt][reg] + bv, 0.f));
      }
    }
  }
}

// ---------- projection GEMM (no LDS, K=128, no bias/relu): out = A @ Wt_half ----------
// Wt has row stride 256 (k-major); pass column offset 0 (Wu) or 128 (Wm).
__global__ __launch_bounds__(256) void proj_mfma_k(
    const ushort_t* __restrict__ A, const ushort_t* __restrict__ Wt, int kofs,
    ushort_t* __restrict__ out, int N)
{
  const int wave = threadIdx.x >> 6;
  const int lane = threadIdx.x & 63;
  const int row0 = (blockIdx.x * 4 + wave) * 32;
  if (row0 >= N) return;
  const int lm = lane & 15;
  const int koff = (lane >> 4) * 8;

  size_t abase[2];
#pragma unroll
  for (int a = 0; a < 2; ++a) abase[a] = (size_t)(row0 + a * 16 + lm) * DH;

  f32x4 acc[2][8];
#pragma unroll
  for (int a = 0; a < 2; ++a)
#pragma unroll
    for (int nt = 0; nt < 8; ++nt) acc[a][nt] = (f32x4){0.f, 0.f, 0.f, 0.f};

#pragma unroll
  for (int ks = 0; ks < 4; ++ks) {
    short8 af[2];
#pragma unroll
    for (int a = 0; a < 2; ++a) af[a] = *(const short8*)(A + abase[a] + ks * 32 + koff);
#pragma unroll
    for (int nt = 0; nt < 8; ++nt) {
      short8 bf = *(const short8*)&Wt[(nt * 16 + lm) * 256 + kofs + ks * 32 + koff];
      acc[0][nt] = __builtin_amdgcn_mfma_f32_16x16x32_bf16(af[0], bf, acc[0][nt], 0, 0, 0);
      acc[1][nt] = __builtin_amdgcn_mfma_f32_16x16x32_bf16(af[1], bf, acc[1][nt], 0, 0, 0);
    }
  }

  const int quad = lane >> 4;
#pragma unroll
  for (int nt = 0; nt < 8; ++nt) {
    int f = nt * 16 + lm;
#pragma unroll
    for (int a = 0; a < 2; ++a) {
#pragma unroll
      for (int reg = 0; reg < 4; ++reg) {
        int r = row0 + a * 16 + quad * 4 + reg;
        out[(size_t)r * DH + f] = f2bf(acc[a][nt][reg]);
      }
    }
  }
}

// ---------- BN epilogue params: S[f], T[f] ----------
__global__ __launch_bounds__(128) void epi_prep_k(
    const float* __restrict__ p1b, const float* __restrict__ gamma,
    const float* __restrict__ beta, const float* __restrict__ mean,
    const float* __restrict__ var, float* __restrict__ SEP, float* __restrict__ TEP)
{
  int f = threadIdx.x;
  float sc = gamma[f] * rsqrtf(var[f] + 1e-5f);
  SEP[f] = sc;
  TEP[f] = (p1b[f] - mean[f]) * sc + beta[f];
}

// ---------- edge predictor over user CSR ----------
// one wave per user row; pu row loaded once; 4 edges per iter (quarter-wave each,
// 16 lanes x 8 feats); out[eid] = sigmoid(sum relu((pu+pm)*S+T)*w2 + b2)*4+1
__global__ __launch_bounds__(256) void ep_k(
    const ushort_t* __restrict__ pu, const ushort_t* __restrict__ pm,
    const int* __restrict__ rp, const int* __restrict__ col, const int* __restrict__ eid,
    const float* __restrict__ SEP, const float* __restrict__ TEP,
    const float* __restrict__ p2W, const float* __restrict__ p2b,
    float* __restrict__ out, int N)
{
  const int wave = threadIdx.x >> 6;
  const int lane = threadIdx.x & 63;
  const int row = blockIdx.x * 4 + wave;
  if (row >= N) return;
  const int lm = lane & 15, q = lane >> 4;
  const int f0 = lm * 8;

  float S[8], base[8], w2[8];
  {
    int4 puv = *(const int4*)(pu + (size_t)row * DH + f0);
    float au[8];
    bf8_to_f32(puv, au);
#pragma unroll
    for (int j = 0; j < 8; ++j) {
      S[j] = SEP[f0 + j];
      base[j] = fmaf(au[j], S[j], TEP[f0 + j]);
      w2[j] = p2W[f0 + j];
    }
  }
  const float bias2 = p2b[0];
  const int b = rp[row], e = rp[row + 1];

  for (int i0 = b; i0 < e; i0 += 4) {
    int i = i0 + q;
    bool valid = i < e;
    int ic = valid ? i : (e - 1);
    int d = col[ic];
    int id = eid[ic];
    int4 pmv = *(const int4*)(pm + (size_t)d * DH + f0);
    float fm[8];
    bf8_to_f32(pmv, fm);
    float p = 0.f;
#pragma unroll
    for (int j = 0; j < 8; ++j) {
      float h = fmaxf(fmaf(fm[j], S[j], base[j]), 0.f);
      p = fmaf(h, w2[j], p);
    }
    p += __shfl_xor(p, 1, 16);
    p += __shfl_xor(p, 2, 16);
    p += __shfl_xor(p, 4, 16);
    p += __shfl_xor(p, 8, 16);
    if (lm == 0 && valid) out[id] = 4.f / (1.f + expf(-(p + bias2))) + 1.f;
  }
}

extern "C" void kernel_launch(void* const* d_in, const int* in_sizes, int n_in,
                              void* d_out, int out_size, void* d_ws, size_t ws_size,
                              hipStream_t stream)
{
  const float* user_feat = (const float*)d_in[0];
  const float* movie_feat = (const float*)d_in[1];
  const float* W_user = (const float*)d_in[2];
  const float* b_user = (const float*)d_in[3];
  const float* W_movie = (const float*)d_in[4];
  const float* b_movie = (const float*)d_in[5];
  const float* u2m1_Wl = (const float*)d_in[6];
  const float* u2m1_bl = (const float*)d_in[7];
  const float* u2m1_Wr = (const float*)d_in[8];
  const float* m2u1_Wl = (const float*)d_in[9];
  const float* m2u1_bl = (const float*)d_in[10];
  const float* m2u1_Wr = (const float*)d_in[11];
  const float* u2m2_Wl = (const float*)d_in[12];
  const float* u2m2_bl = (const float*)d_in[13];
  const float* u2m2_Wr = (const float*)d_in[14];
  const float* m2u2_Wl = (const float*)d_in[15];
  const float* m2u2_bl = (const float*)d_in[16];
  const float* m2u2_Wr = (const float*)d_in[17];
  const float* u2u_Wl = (const float*)d_in[18];
  const float* u2u_bl = (const float*)d_in[19];
  const float* u2u_Wr = (const float*)d_in[20];
  const float* p1_W = (const float*)d_in[21];
  const float* p1_b = (const float*)d_in[22];
  const float* bn_gamma = (const float*)d_in[23];
  const float* bn_beta = (const float*)d_in[24];
  const float* bn_mean = (const float*)d_in[25];
  const float* bn_var = (const float*)d_in[26];
  const float* p2_W = (const float*)d_in[27];
  const float* p2_b = (const float*)d_in[28];
  const int* rated_src = (const int*)d_in[29];
  const int* rated_dst = (const int*)d_in[30];
  const int* uu_src = (const int*)d_in[31];
  const int* uu_dst = (const int*)d_in[32];

  // ---- workspace layout ----
  ushort_t* ux = (ushort_t*)d_ws;                       // NU*128
  ushort_t* mx = ux + (size_t)NUSR * DH;                // NM*128
  ushort_t* agg = mx + (size_t)NMOV * DH;               // NU*128 (reused as pu)
  ushort_t* pm = agg + (size_t)NUSR * DH;               // NM*128
  ushort_t* Wt = pm + (size_t)NMOV * DH;                // 6 * 128*256
  float* SEP = (float*)(Wt + 6 * 32768);                // 128
  float* TEP = SEP + DH;                                // 128
  int* rp_m = (int*)(TEP + DH);                         // NM+1
  int* rp_u = rp_m + (NMOV + 1);                        // NU+1
  int* rp_uu = rp_u + (NUSR + 1);                       // NU+1
  int* col_m = rp_uu + (NUSR + 1);                      // E
  int* col_u = col_m + NEDG;                            // E
  int* eid_u = col_u + NEDG;                            // E
  int* col_uu = eid_u + NEDG;                           // EUU
  int* cnt_u = col_uu + NEUU;                           // NU
  int* cnt_m = cnt_u + NUSR;                            // NM (contiguous with cnt_u)

  ushort_t* Wt_u2m1 = Wt + 0 * 32768;
  ushort_t* Wt_m2u1 = Wt + 1 * 32768;
  ushort_t* Wt_u2m2 = Wt + 2 * 32768;
  ushort_t* Wt_m2u2 = Wt + 3 * 32768;
  ushort_t* Wt_u2u  = Wt + 4 * 32768;
  ushort_t* Wt_p1   = Wt + 5 * 32768;
  ushort_t* pu = agg;  // alias: agg is dead after the last sage layer

  // ---- weight prep ----
  prep_w_k<<<128, 256, 0, stream>>>(u2m1_Wl, u2m1_Wr, Wt_u2m1);
  prep_w_k<<<128, 256, 0, stream>>>(m2u1_Wl, m2u1_Wr, Wt_m2u1);
  prep_w_k<<<128, 256, 0, stream>>>(u2m2_Wl, u2m2_Wr, Wt_u2m2);
  prep_w_k<<<128, 256, 0, stream>>>(m2u2_Wl, m2u2_Wr, Wt_m2u2);
  prep_w_k<<<128, 256, 0, stream>>>(u2u_Wl, u2u_Wr, Wt_u2u);
  prep_w_k<<<128, 256, 0, stream>>>(p1_W, p1_W + DH * DH, Wt_p1);
  epi_prep_k<<<1, 128, 0, stream>>>(p1_b, bn_gamma, bn_beta, bn_mean, bn_var, SEP, TEP);

  // ---- input linears ----
  lin_relu_bf_k<64><<<NUSR / 32, 256, 0, stream>>>(user_feat, W_user, b_user, ux, NUSR);
  lin_relu_bf_k<128><<<NMOV / 32, 256, 0, stream>>>(movie_feat, W_movie, b_movie, mx, NMOV);

  // ---- CSR builds ----
  const int gcE = (NEDG + 255) / 256, gcU = (NEUU + 255) / 256;
  hipMemsetAsync(cnt_u, 0, (size_t)(NUSR + NMOV) * sizeof(int), stream);
  count2_k<<<gcE, 256, 0, stream>>>(rated_src, rated_dst, cnt_u, cnt_m, NEDG);
  scan_k<<<1, 1024, 0, stream>>>(cnt_m, rp_m, NMOV);
  scan_k<<<1, 1024, 0, stream>>>(cnt_u, rp_u, NUSR);
  hipMemsetAsync(cnt_u, 0, (size_t)(NUSR + NMOV) * sizeof(int), stream);
  fill_k<<<gcE, 256, 0, stream>>>(rated_dst, rated_src, rp_m, cnt_m, col_m, nullptr, NEDG);
  fill_k<<<gcE, 256, 0, stream>>>(rated_src, rated_dst, rp_u, cnt_u, col_u, eid_u, NEDG);
  hipMemsetAsync(cnt_u, 0, (size_t)NUSR * sizeof(int), stream);
  count_k<<<gcU, 256, 0, stream>>>(uu_dst, cnt_u, NEUU);
  scan_k<<<1, 1024, 0, stream>>>(cnt_u, rp_uu, NUSR);
  hipMemsetAsync(cnt_u, 0, (size_t)NUSR * sizeof(int), stream);
  fill_k<<<gcU, 256, 0, stream>>>(uu_dst, uu_src, rp_uu, cnt_u, col_uu, nullptr, NEUU);

  // ---- 5 SAGE layers ----
  const int gaM = (NMOV + 15) / 16, gaU = (NUSR + 15) / 16;
  const int gmM = (NMOV + 127) / 128, gmU = (NUSR + 127) / 128;
  // u2m1
  agg_mean4_k<<<gaM, 256, 0, stream>>>(ux, rp_m, col_m, agg, NMOV);
  sage_mfma_k<<<gmM, 256, 0, stream>>>(agg, mx, Wt_u2m1, u2m1_bl, mx, NMOV);
  // m2u1
  agg_mean4_k<<<gaU, 256, 0, stream>>>(mx, rp_u, col_u, agg, NUSR);
  sage_mfma_k<<<gmU, 256, 0, stream>>>(agg, ux, Wt_m2u1, m2u1_bl, ux, NUSR);
  // u2m2
  agg_mean4_k<<<gaM, 256, 0, stream>>>(ux, rp_m, col_m, agg, NMOV);
  sage_mfma_k<<<gmM, 256, 0, stream>>>(agg, mx, Wt_u2m2, u2m2_bl, mx, NMOV);
  // m2u2
  agg_mean4_k<<<gaU, 256, 0, stream>>>(mx, rp_u, col_u, agg, NUSR);
  sage_mfma_k<<<gmU, 256, 0, stream>>>(agg, ux, Wt_m2u2, m2u2_bl, ux, NUSR);
  // u2u
  agg_mean4_k<<<gaU, 256, 0, stream>>>(ux, rp_uu, col_uu, agg, NUSR);
  sage_mfma_k<<<gmU, 256, 0, stream>>>(agg, ux, Wt_u2u, u2u_bl, ux, NUSR);

  // ---- factored edge MLP: node projections then CSR edge predictor ----
  proj_mfma_k<<<gmU, 256, 0, stream>>>(ux, Wt_p1, 0, pu, NUSR);    // pu = ux @ Wu (overwrites agg)
  proj_mfma_k<<<gmM, 256, 0, stream>>>(mx, Wt_p1, DH, pm, NMOV);   // pm = mx @ Wm
  ep_k<<<(NUSR + 3) / 4, 256, 0, stream>>>(
      pu, pm, rp_u, col_u, eid_u, SEP, TEP, p2_W, p2_b, (float*)d_out, NUSR);
}

// Round 4
// 982.453 us; speedup vs baseline: 7.8490x; 1.2858x over previous
//
#include <hip/hip_runtime.h>
#include <cmath>

// SimpleHeteroGNN on MI355X — Round 4.
// R3 post-mortem: 3x single-block scan_k = 420 us (33% of launch) at 0.15%
// occupancy. This round: multi-block 3-phase segmented scan (one pass for all
// three CSR histograms), fused count/fill/prep kernels, agg edge-unroll 4.

#define NUSR 100000
#define NMOV 20000
#define NEDG 1000000
#define NEUU 500000
#define DH 128

// segmented scan geometry: [cnt_m(NMOV) | cnt_u(NUSR) | cnt_uu(NUSR)]
#define SCHUNK 4096
#define NB_M 5      // ceil(NMOV/SCHUNK)
#define NB_U 25     // ceil(NUSR/SCHUNK)
#define NB_TOT 55   // NB_M + 2*NB_U

typedef unsigned short ushort_t;
typedef __attribute__((ext_vector_type(8))) short short8;
typedef __attribute__((ext_vector_type(4))) float f32x4;

__device__ __forceinline__ ushort_t f2bf(float f) {
  unsigned u = __float_as_uint(f);
  u += 0x7FFFu + ((u >> 16) & 1u);
  return (ushort_t)(u >> 16);
}
__device__ __forceinline__ void bf8_to_f32(int4 v, float* f) {
  unsigned a = (unsigned)v.x, b = (unsigned)v.y, c = (unsigned)v.z, d = (unsigned)v.w;
  f[0] = __uint_as_float(a << 16); f[1] = __uint_as_float(a & 0xFFFF0000u);
  f[2] = __uint_as_float(b << 16); f[3] = __uint_as_float(b & 0xFFFF0000u);
  f[4] = __uint_as_float(c << 16); f[5] = __uint_as_float(c & 0xFFFF0000u);
  f[6] = __uint_as_float(d << 16); f[7] = __uint_as_float(d & 0xFFFF0000u);
}

// ---------- fused weight prep + BN epilogue params ----------
struct PrepArgs {
  const float* Wl[6];
  const float* Wr[6];
};
__global__ __launch_bounds__(256) void prep_all_k(
    PrepArgs pa, ushort_t* __restrict__ Wt,
    const float* __restrict__ p1b, const float* __restrict__ gamma,
    const float* __restrict__ beta, const float* __restrict__ mean,
    const float* __restrict__ var, const float* __restrict__ p2W_in,
    float* __restrict__ SEP, float* __restrict__ TEP)
{
  int blk = blockIdx.x;
  if (blk < 768) {
    int wi = blk >> 7;
    int idx = (blk & 127) * 256 + threadIdx.x;  // 0..32767
    int n = idx >> 8, k = idx & 255;
    const float* Wl = pa.Wl[wi];
    const float* Wr = pa.Wr[wi];
    float v = (k < DH) ? Wl[k * DH + n] : Wr[(k - DH) * DH + n];
    Wt[(size_t)wi * 32768 + n * 256 + k] = f2bf(v);
  } else {
    int f = threadIdx.x;
    if (f < DH) {
      float sc = gamma[f] * rsqrtf(var[f] + 1e-5f);
      SEP[f] = sc;
      TEP[f] = (p1b[f] - mean[f]) * sc + beta[f];
    }
  }
}

// ---------- input linear: Y = relu(X @ W + b), bf16 out ----------
template <int K>
__global__ __launch_bounds__(256) void lin_relu_bf_k(
    const float* __restrict__ X, const float* __restrict__ W,
    const float* __restrict__ b, ushort_t* __restrict__ Y, int N)
{
  const int wave = threadIdx.x >> 6;
  const int lane = threadIdx.x & 63;
  const long row0 = ((long)blockIdx.x * 4 + wave) * 8;
  if (row0 >= N) return;
  const int c0 = lane, c1 = lane + 64;
  float acc[8][2];
#pragma unroll
  for (int r = 0; r < 8; ++r) { acc[r][0] = 0.f; acc[r][1] = 0.f; }
#pragma unroll 4
  for (int k = 0; k < K; ++k) {
    float w0 = W[k * DH + c0];
    float w1 = W[k * DH + c1];
#pragma unroll
    for (int r = 0; r < 8; ++r) {
      float xv = X[(row0 + r) * K + k];  // wave-uniform -> scalar load
      acc[r][0] = fmaf(xv, w0, acc[r][0]);
      acc[r][1] = fmaf(xv, w1, acc[r][1]);
    }
  }
  float b0 = b[c0], b1 = b[c1];
#pragma unroll
  for (int r = 0; r < 8; ++r) {
    Y[(row0 + r) * DH + c0] = f2bf(fmaxf(acc[r][0] + b0, 0.f));
    Y[(row0 + r) * DH + c1] = f2bf(fmaxf(acc[r][1] + b1, 0.f));
  }
}

// ---------- fused histogram for all 3 CSRs ----------
__global__ __launch_bounds__(256) void count_all_k(
    const int* __restrict__ rsrc, const int* __restrict__ rdst,
    const int* __restrict__ usrc, const int* __restrict__ udst,
    int* __restrict__ cnt_m, int* __restrict__ cnt_u, int* __restrict__ cnt_uu)
{
  int e = blockIdx.x * 256 + threadIdx.x;
  if (e < NEDG) {
    atomicAdd(&cnt_u[rsrc[e]], 1);
    atomicAdd(&cnt_m[rdst[e]], 1);
  }
  if (e < NEUU) atomicAdd(&cnt_uu[udst[e]], 1);
}

// ---------- segmented multi-block scan: phase A (block sums) ----------
__device__ __forceinline__ void seg_map(int b, int& seg, int& lb, int& segbase, int& segn) {
  if (b < NB_M)            { seg = 0; lb = b;              segbase = 0;           segn = NMOV; }
  else if (b < NB_M + NB_U){ seg = 1; lb = b - NB_M;       segbase = NMOV;        segn = NUSR; }
  else                     { seg = 2; lb = b - NB_M - NB_U;segbase = NMOV + NUSR; segn = NUSR; }
}

__global__ __launch_bounds__(256) void scanA_k(
    const int* __restrict__ cntbuf, int* __restrict__ bpart)
{
  int seg, lb, segbase, segn;
  seg_map(blockIdx.x, seg, lb, segbase, segn);
  int start = lb * SCHUNK + threadIdx.x * 16;
  int s = 0;
#pragma unroll
  for (int j = 0; j < 16; ++j) {
    int i = start + j;
    if (i < segn) s += cntbuf[segbase + i];
  }
  __shared__ int red[256];
  red[threadIdx.x] = s;
  __syncthreads();
  for (int off = 128; off > 0; off >>= 1) {
    if (threadIdx.x < off) red[threadIdx.x] += red[threadIdx.x + off];
    __syncthreads();
  }
  if (threadIdx.x == 0) bpart[blockIdx.x] = red[0];
}

// ---------- phase B: scan the 55 partials (segment-reset), write totals ----------
__global__ __launch_bounds__(64) void scanB_k(
    int* __restrict__ bpart, int* __restrict__ rp_m,
    int* __restrict__ rp_u, int* __restrict__ rp_uu)
{
  if (threadIdx.x != 0) return;
  int acc = 0;
  for (int b = 0; b < NB_M; ++b) { int v = bpart[b]; bpart[b] = acc; acc += v; }
  rp_m[NMOV] = acc;
  acc = 0;
  for (int b = NB_M; b < NB_M + NB_U; ++b) { int v = bpart[b]; bpart[b] = acc; acc += v; }
  rp_u[NUSR] = acc;
  acc = 0;
  for (int b = NB_M + NB_U; b < NB_TOT; ++b) { int v = bpart[b]; bpart[b] = acc; acc += v; }
  rp_uu[NUSR] = acc;
}

// ---------- phase C: per-block local scan + offset -> rowptr ----------
__global__ __launch_bounds__(256) void scanC_k(
    const int* __restrict__ cntbuf, const int* __restrict__ bpart,
    int* __restrict__ rp_m, int* __restrict__ rp_u, int* __restrict__ rp_uu)
{
  int seg, lb, segbase, segn;
  seg_map(blockIdx.x, seg, lb, segbase, segn);
  int* rp = (seg == 0) ? rp_m : ((seg == 1) ? rp_u : rp_uu);
  const int t = threadIdx.x;
  int start = lb * SCHUNK + t * 16;
  int vals[16];
  int s = 0;
#pragma unroll
  for (int j = 0; j < 16; ++j) {
    int i = start + j;
    vals[j] = (i < segn) ? cntbuf[segbase + i] : 0;
    s += vals[j];
  }
  __shared__ int part[256];
  part[t] = s;
  __syncthreads();
  for (int off = 1; off < 256; off <<= 1) {
    int v = (t >= off) ? part[t - off] : 0;
    __syncthreads();
    part[t] += v;
    __syncthreads();
  }
  int excl = part[t] - s + bpart[blockIdx.x];
#pragma unroll
  for (int j = 0; j < 16; ++j) {
    int i = start + j;
    if (i < segn) rp[i] = excl;
    excl += vals[j];
  }
}

// ---------- fused fill for all 3 CSRs ----------
__global__ __launch_bounds__(256) void fill_all_k(
    const int* __restrict__ rsrc, const int* __restrict__ rdst,
    const int* __restrict__ usrc, const int* __restrict__ udst,
    const int* __restrict__ rp_m, const int* __restrict__ rp_u, const int* __restrict__ rp_uu,
    int* __restrict__ cur_m, int* __restrict__ cur_u, int* __restrict__ cur_uu,
    int* __restrict__ col_m, int* __restrict__ col_u, int* __restrict__ eid_u,
    int* __restrict__ col_uu)
{
  int e = blockIdx.x * 256 + threadIdx.x;
  if (e < NEDG) {
    int s = rsrc[e], d = rdst[e];
    int pm_ = rp_m[d] + atomicAdd(&cur_m[d], 1);
    col_m[pm_] = s;
    int pu_ = rp_u[s] + atomicAdd(&cur_u[s], 1);
    col_u[pu_] = d;
    eid_u[pu_] = e;
  }
  if (e < NEUU) {
    int s = usrc[e], d = udst[e];
    int p = rp_uu[d] + atomicAdd(&cur_uu[d], 1);
    col_uu[p] = s;
  }
}

// ---------- gather-mean: 4 rows/wave (quarter each), edge-unroll 4 ----------
__global__ __launch_bounds__(256) void agg_mean4_k(
    const ushort_t* __restrict__ x, const int* __restrict__ rowptr,
    const int* __restrict__ col, ushort_t* __restrict__ out, int N)
{
  const int wave = threadIdx.x >> 6;
  const int lane = threadIdx.x & 63;
  const int lm = lane & 15, q = lane >> 4;
  const int row = blockIdx.x * 16 + wave * 4 + q;
  if (row >= N) return;
  const int b = rowptr[row], e = rowptr[row + 1];
  float a[8];
#pragma unroll
  for (int j = 0; j < 8; ++j) a[j] = 0.f;
  int i = b;
  for (; i + 3 < e; i += 4) {
    int s0 = col[i], s1 = col[i + 1], s2 = col[i + 2], s3 = col[i + 3];
    int4 v0 = *(const int4*)(x + (size_t)s0 * DH + lm * 8);
    int4 v1 = *(const int4*)(x + (size_t)s1 * DH + lm * 8);
    int4 v2 = *(const int4*)(x + (size_t)s2 * DH + lm * 8);
    int4 v3 = *(const int4*)(x + (size_t)s3 * DH + lm * 8);
    float f0[8], f1[8], f2[8], f3[8];
    bf8_to_f32(v0, f0); bf8_to_f32(v1, f1); bf8_to_f32(v2, f2); bf8_to_f32(v3, f3);
#pragma unroll
    for (int j = 0; j < 8; ++j) a[j] += (f0[j] + f1[j]) + (f2[j] + f3[j]);
  }
  for (; i < e; ++i) {
    int4 v0 = *(const int4*)(x + (size_t)col[i] * DH + lm * 8);
    float f0[8];
    bf8_to_f32(v0, f0);
#pragma unroll
    for (int j = 0; j < 8; ++j) a[j] += f0[j];
  }
  int deg = e - b;
  float inv = 1.f / (float)(deg > 1 ? deg : 1);
  unsigned p0 = f2bf(a[0] * inv) | ((unsigned)f2bf(a[1] * inv) << 16);
  unsigned p1 = f2bf(a[2] * inv) | ((unsigned)f2bf(a[3] * inv) << 16);
  unsigned p2 = f2bf(a[4] * inv) | ((unsigned)f2bf(a[5] * inv) << 16);
  unsigned p3 = f2bf(a[6] * inv) | ((unsigned)f2bf(a[7] * inv) << 16);
  *(int4*)(out + (size_t)row * DH + lm * 8) = make_int4(p0, p1, p2, p3);
}

// ---------- SAGE update GEMM (no LDS): out = relu([A0|A1] @ WtT + bl) ----------
__global__ __launch_bounds__(256) void sage_mfma_k(
    const ushort_t* __restrict__ A0, const ushort_t* __restrict__ A1,
    const ushort_t* __restrict__ Wt, const float* __restrict__ bl,
    ushort_t* __restrict__ out, int N)
{
  const int wave = threadIdx.x >> 6;
  const int lane = threadIdx.x & 63;
  const int row0 = (blockIdx.x * 4 + wave) * 32;
  if (row0 >= N) return;
  const int lm = lane & 15;
  const int koff = (lane >> 4) * 8;

  size_t abase[2];
#pragma unroll
  for (int a = 0; a < 2; ++a) abase[a] = (size_t)(row0 + a * 16 + lm) * DH;

  f32x4 acc[2][8];
#pragma unroll
  for (int a = 0; a < 2; ++a)
#pragma unroll
    for (int nt = 0; nt < 8; ++nt) acc[a][nt] = (f32x4){0.f, 0.f, 0.f, 0.f};

#pragma unroll
  for (int ks = 0; ks < 8; ++ks) {
    short8 af[2];
#pragma unroll
    for (int a = 0; a < 2; ++a) {
      const ushort_t* p = (ks < 4) ? (A0 + abase[a] + ks * 32 + koff)
                                   : (A1 + abase[a] + (ks - 4) * 32 + koff);
      af[a] = *(const short8*)p;
    }
#pragma unroll
    for (int nt = 0; nt < 8; ++nt) {
      short8 bf = *(const short8*)&Wt[(nt * 16 + lm) * 256 + ks * 32 + koff];
      acc[0][nt] = __builtin_amdgcn_mfma_f32_16x16x32_bf16(af[0], bf, acc[0][nt], 0, 0, 0);
      acc[1][nt] = __builtin_amdgcn_mfma_f32_16x16x32_bf16(af[1], bf, acc[1][nt], 0, 0, 0);
    }
  }

  const int quad = lane >> 4;
#pragma unroll
  for (int nt = 0; nt < 8; ++nt) {
    int f = nt * 16 + lm;
    float bv = bl[f];
#pragma unroll
    for (int a = 0; a < 2; ++a) {
#pragma unroll
      for (int reg = 0; reg < 4; ++reg) {
        int r = row0 + a * 16 + quad * 4 + reg;
        out[(size_t)r * DH + f] = f2bf(fmaxf(acc[a][nt][reg] + bv, 0.f));
      }
    }
  }
}

// ---------- projection GEMM (no LDS, K=128): out = A @ Wt[:, kofs:kofs+128] ----------
__global__ __launch_bounds__(256) void proj_mfma_k(
    const ushort_t* __restrict__ A, const ushort_t* __restrict__ Wt, int kofs,
    ushort_t* __restrict__ out, int N)
{
  const int wave = threadIdx.x >> 6;
  const int lane = threadIdx.x & 63;
  const int row0 = (blockIdx.x * 4 + wave) * 32;
  if (row0 >= N) return;
  const int lm = lane & 15;
  const int koff = (lane >> 4) * 8;

  size_t abase[2];
#pragma unroll
  for (int a = 0; a < 2; ++a) abase[a] = (size_t)(row0 + a * 16 + lm) * DH;

  f32x4 acc[2][8];
#pragma unroll
  for (int a = 0; a < 2; ++a)
#pragma unroll
    for (int nt = 0; nt < 8; ++nt) acc[a][nt] = (f32x4){0.f, 0.f, 0.f, 0.f};

#pragma unroll
  for (int ks = 0; ks < 4; ++ks) {
    short8 af[2];
#pragma unroll
    for (int a = 0; a < 2; ++a) af[a] = *(const short8*)(A + abase[a] + ks * 32 + koff);
#pragma unroll
    for (int nt = 0; nt < 8; ++nt) {
      short8 bf = *(const short8*)&Wt[(nt * 16 + lm) * 256 + kofs + ks * 32 + koff];
      acc[0][nt] = __builtin_amdgcn_mfma_f32_16x16x32_bf16(af[0], bf, acc[0][nt], 0, 0, 0);
      acc[1][nt] = __builtin_amdgcn_mfma_f32_16x16x32_bf16(af[1], bf, acc[1][nt], 0, 0, 0);
    }
  }

  const int quad = lane >> 4;
#pragma unroll
  for (int nt = 0; nt < 8; ++nt) {
    int f = nt * 16 + lm;
#pragma unroll
    for (int a = 0; a < 2; ++a) {
#pragma unroll
      for (int reg = 0; reg < 4; ++reg) {
        int r = row0 + a * 16 + quad * 4 + reg;
        out[(size_t)r * DH + f] = f2bf(acc[a][nt][reg]);
      }
    }
  }
}

// ---------- edge predictor over user CSR ----------
__global__ __launch_bounds__(256) void ep_k(
    const ushort_t* __restrict__ pu, const ushort_t* __restrict__ pm,
    const int* __restrict__ rp, const int* __restrict__ col, const int* __restrict__ eid,
    const float* __restrict__ SEP, const float* __restrict__ TEP,
    const float* __restrict__ p2W, const float* __restrict__ p2b,
    float* __restrict__ out, int N)
{
  const int wave = threadIdx.x >> 6;
  const int lane = threadIdx.x & 63;
  const int row = blockIdx.x * 4 + wave;
  if (row >= N) return;
  const int lm = lane & 15, q = lane >> 4;
  const int f0 = lm * 8;

  float S[8], base[8], w2[8];
  {
    int4 puv = *(const int4*)(pu + (size_t)row * DH + f0);
    float au[8];
    bf8_to_f32(puv, au);
#pragma unroll
    for (int j = 0; j < 8; ++j) {
      S[j] = SEP[f0 + j];
      base[j] = fmaf(au[j], S[j], TEP[f0 + j]);
      w2[j] = p2W[f0 + j];
    }
  }
  const float bias2 = p2b[0];
  const int b = rp[row], e = rp[row + 1];

  for (int i0 = b; i0 < e; i0 += 4) {
    int i = i0 + q;
    bool valid = i < e;
    int ic = valid ? i : (e - 1);
    int d = col[ic];
    int id = eid[ic];
    int4 pmv = *(const int4*)(pm + (size_t)d * DH + f0);
    float fm[8];
    bf8_to_f32(pmv, fm);
    float p = 0.f;
#pragma unroll
    for (int j = 0; j < 8; ++j) {
      float h = fmaxf(fmaf(fm[j], S[j], base[j]), 0.f);
      p = fmaf(h, w2[j], p);
    }
    p += __shfl_xor(p, 1, 16);
    p += __shfl_xor(p, 2, 16);
    p += __shfl_xor(p, 4, 16);
    p += __shfl_xor(p, 8, 16);
    if (lm == 0 && valid) out[id] = 4.f / (1.f + expf(-(p + bias2))) + 1.f;
  }
}

extern "C" void kernel_launch(void* const* d_in, const int* in_sizes, int n_in,
                              void* d_out, int out_size, void* d_ws, size_t ws_size,
                              hipStream_t stream)
{
  const float* user_feat = (const float*)d_in[0];
  const float* movie_feat = (const float*)d_in[1];
  const float* W_user = (const float*)d_in[2];
  const float* b_user = (const float*)d_in[3];
  const float* W_movie = (const float*)d_in[4];
  const float* b_movie = (const float*)d_in[5];
  const float* u2m1_Wl = (const float*)d_in[6];
  const float* u2m1_bl = (const float*)d_in[7];
  const float* u2m1_Wr = (const float*)d_in[8];
  const float* m2u1_Wl = (const float*)d_in[9];
  const float* m2u1_bl = (const float*)d_in[10];
  const float* m2u1_Wr = (const float*)d_in[11];
  const float* u2m2_Wl = (const float*)d_in[12];
  const float* u2m2_bl = (const float*)d_in[13];
  const float* u2m2_Wr = (const float*)d_in[14];
  const float* m2u2_Wl = (const float*)d_in[15];
  const float* m2u2_bl = (const float*)d_in[16];
  const float* m2u2_Wr = (const float*)d_in[17];
  const float* u2u_Wl = (const float*)d_in[18];
  const float* u2u_bl = (const float*)d_in[19];
  const float* u2u_Wr = (const float*)d_in[20];
  const float* p1_W = (const float*)d_in[21];
  const float* p1_b = (const float*)d_in[22];
  const float* bn_gamma = (const float*)d_in[23];
  const float* bn_beta = (const float*)d_in[24];
  const float* bn_mean = (const float*)d_in[25];
  const float* bn_var = (const float*)d_in[26];
  const float* p2_W = (const float*)d_in[27];
  const float* p2_b = (const float*)d_in[28];
  const int* rated_src = (const int*)d_in[29];
  const int* rated_dst = (const int*)d_in[30];
  const int* uu_src = (const int*)d_in[31];
  const int* uu_dst = (const int*)d_in[32];

  // ---- workspace layout ----
  ushort_t* ux = (ushort_t*)d_ws;                       // NU*128
  ushort_t* mx = ux + (size_t)NUSR * DH;                // NM*128
  ushort_t* agg = mx + (size_t)NMOV * DH;               // NU*128 (reused as pu)
  ushort_t* pm = agg + (size_t)NUSR * DH;               // NM*128
  ushort_t* Wt = pm + (size_t)NMOV * DH;                // 6 * 32768
  float* SEP = (float*)(Wt + 6 * 32768);                // 128
  float* TEP = SEP + DH;                                // 128
  int* rp_m = (int*)(TEP + DH);                         // NM+1
  int* rp_u = rp_m + (NMOV + 1);                        // NU+1
  int* rp_uu = rp_u + (NUSR + 1);                       // NU+1
  int* col_m = rp_uu + (NUSR + 1);                      // E
  int* col_u = col_m + NEDG;                            // E
  int* eid_u = col_u + NEDG;                            // E
  int* col_uu = eid_u + NEDG;                           // EUU
  int* cntbuf = col_uu + NEUU;                          // NMOV+2*NUSR
  int* curbuf = cntbuf + (NMOV + 2 * NUSR);             // NMOV+2*NUSR
  int* bpart = curbuf + (NMOV + 2 * NUSR);              // 64
  int* cnt_m = cntbuf;
  int* cnt_u = cntbuf + NMOV;
  int* cnt_uu = cntbuf + NMOV + NUSR;
  int* cur_m = curbuf;
  int* cur_u = curbuf + NMOV;
  int* cur_uu = curbuf + NMOV + NUSR;

  ushort_t* Wt_u2m1 = Wt + 0 * 32768;
  ushort_t* Wt_m2u1 = Wt + 1 * 32768;
  ushort_t* Wt_u2m2 = Wt + 2 * 32768;
  ushort_t* Wt_m2u2 = Wt + 3 * 32768;
  ushort_t* Wt_u2u  = Wt + 4 * 32768;
  ushort_t* Wt_p1   = Wt + 5 * 32768;
  ushort_t* pu = agg;  // alias: agg dead after last sage layer

  // ---- fused weight prep + BN params ----
  PrepArgs pa;
  pa.Wl[0] = u2m1_Wl; pa.Wr[0] = u2m1_Wr;
  pa.Wl[1] = m2u1_Wl; pa.Wr[1] = m2u1_Wr;
  pa.Wl[2] = u2m2_Wl; pa.Wr[2] = u2m2_Wr;
  pa.Wl[3] = m2u2_Wl; pa.Wr[3] = m2u2_Wr;
  pa.Wl[4] = u2u_Wl;  pa.Wr[4] = u2u_Wr;
  pa.Wl[5] = p1_W;    pa.Wr[5] = p1_W + DH * DH;
  prep_all_k<<<769, 256, 0, stream>>>(pa, Wt, p1_b, bn_gamma, bn_beta, bn_mean,
                                      bn_var, p2_W, SEP, TEP);

  // ---- input linears ----
  lin_relu_bf_k<64><<<NUSR / 32, 256, 0, stream>>>(user_feat, W_user, b_user, ux, NUSR);
  lin_relu_bf_k<128><<<NMOV / 32, 256, 0, stream>>>(movie_feat, W_movie, b_movie, mx, NMOV);

  // ---- CSR builds: one memset, fused count, 3-phase scan, fused fill ----
  hipMemsetAsync(cntbuf, 0, (size_t)2 * (NMOV + 2 * NUSR) * sizeof(int), stream);
  const int gcE = (NEDG + 255) / 256;
  count_all_k<<<gcE, 256, 0, stream>>>(rated_src, rated_dst, uu_src, uu_dst,
                                       cnt_m, cnt_u, cnt_uu);
  scanA_k<<<NB_TOT, 256, 0, stream>>>(cntbuf, bpart);
  scanB_k<<<1, 64, 0, stream>>>(bpart, rp_m, rp_u, rp_uu);
  scanC_k<<<NB_TOT, 256, 0, stream>>>(cntbuf, bpart, rp_m, rp_u, rp_uu);
  fill_all_k<<<gcE, 256, 0, stream>>>(rated_src, rated_dst, uu_src, uu_dst,
                                      rp_m, rp_u, rp_uu, cur_m, cur_u, cur_uu,
                                      col_m, col_u, eid_u, col_uu);

  // ---- 5 SAGE layers ----
  const int gaM = (NMOV + 15) / 16, gaU = (NUSR + 15) / 16;
  const int gmM = (NMOV + 127) / 128, gmU = (NUSR + 127) / 128;
  // u2m1
  agg_mean4_k<<<gaM, 256, 0, stream>>>(ux, rp_m, col_m, agg, NMOV);
  sage_mfma_k<<<gmM, 256, 0, stream>>>(agg, mx, Wt_u2m1, u2m1_bl, mx, NMOV);
  // m2u1
  agg_mean4_k<<<gaU, 256, 0, stream>>>(mx, rp_u, col_u, agg, NUSR);
  sage_mfma_k<<<gmU, 256, 0, stream>>>(agg, ux, Wt_m2u1, m2u1_bl, ux, NUSR);
  // u2m2
  agg_mean4_k<<<gaM, 256, 0, stream>>>(ux, rp_m, col_m, agg, NMOV);
  sage_mfma_k<<<gmM, 256, 0, stream>>>(agg, mx, Wt_u2m2, u2m2_bl, mx, NMOV);
  // m2u2
  agg_mean4_k<<<gaU, 256, 0, stream>>>(mx, rp_u, col_u, agg, NUSR);
  sage_mfma_k<<<gmU, 256, 0, stream>>>(agg, ux, Wt_m2u2, m2u2_bl, ux, NUSR);
  // u2u
  agg_mean4_k<<<gaU, 256, 0, stream>>>(ux, rp_uu, col_uu, agg, NUSR);
  sage_mfma_k<<<gmU, 256, 0, stream>>>(agg, ux, Wt_u2u, u2u_bl, ux, NUSR);

  // ---- factored edge MLP ----
  proj_mfma_k<<<gmU, 256, 0, stream>>>(ux, Wt_p1, 0, pu, NUSR);
  proj_mfma_k<<<gmM, 256, 0, stream>>>(mx, Wt_p1, DH, pm, NMOV);
  ep_k<<<(NUSR + 3) / 4, 256, 0, stream>>>(
      pu, pm, rp_u, col_u, eid_u, SEP, TEP, p2_W, p2_b, (float*)d_out, NUSR);
}